// Round 2
// 3992.085 us; speedup vs baseline: 2.4895x; 2.4895x over previous
//
#include <hip/hip_runtime.h>
#include <cmath>

// Problem constants (fixed by setup_inputs)
constexpr int B = 32, S = 1024, I = 512, H = 1024;
constexpr float DT = 0.05f;

// ---------------------------------------------------------------------------
// Phase 1: h_in_all[M=B*S][H] = x[M][I] @ W_in[I][H], fp32, written into the
// `outs` region of d_out (the scan consumes/overwrites it in place).
// 64x64 tile, BK=16, 256 threads, 4x4 micro-tile. (unchanged, ~0.6 ms)
// ---------------------------------------------------------------------------
__global__ __launch_bounds__(256) void gemm_in(const float* __restrict__ A,
                                               const float* __restrict__ Bw,
                                               float* __restrict__ C) {
    const int bx = blockIdx.x;
    const int nb = bx & 15;       // 1024/64 = 16 col tiles
    const int mb = bx >> 4;       // 32768/64 = 512 row tiles
    const int t  = threadIdx.x;
    const int tx = t & 15, ty = t >> 4;

    __shared__ __align__(16) float As[16][68];
    __shared__ __align__(16) float Bs[16][68];

    float acc[4][4] = {};
    const int row0 = mb * 64, col0 = nb * 64;

    for (int kt = 0; kt < I; kt += 16) {
        {
            const int m  = t >> 2;
            const int kq = (t & 3) * 4;
            const float4 a = *(const float4*)(A + (size_t)(row0 + m) * I + kt + kq);
            As[kq + 0][m] = a.x; As[kq + 1][m] = a.y;
            As[kq + 2][m] = a.z; As[kq + 3][m] = a.w;
            const int kk = t >> 4;
            const int n4 = (t & 15) * 4;
            *(float4*)&Bs[kk][n4] =
                *(const float4*)(Bw + (size_t)(kt + kk) * H + col0 + n4);
        }
        __syncthreads();
#pragma unroll
        for (int kk = 0; kk < 16; ++kk) {
            const float4 av = *(const float4*)&As[kk][ty * 4];
            const float4 bv = *(const float4*)&Bs[kk][tx * 4];
            const float ar[4] = {av.x, av.y, av.z, av.w};
            const float br[4] = {bv.x, bv.y, bv.z, bv.w};
#pragma unroll
            for (int i = 0; i < 4; ++i)
#pragma unroll
                for (int j = 0; j < 4; ++j) acc[i][j] += ar[i] * br[j];
        }
        __syncthreads();
    }
#pragma unroll
    for (int i = 0; i < 4; ++i) {
        float4 v = make_float4(acc[i][0], acc[i][1], acc[i][2], acc[i][3]);
        *(float4*)(C + (size_t)(row0 + ty * 4 + i) * H + col0 + tx * 4) = v;
    }
}

// fma of scalar into 4-wide accumulator
__device__ __forceinline__ void fma4(float4& acc, float sc, const float4 wv) {
    acc.x = fmaf(sc, wv.x, acc.x);
    acc.y = fmaf(sc, wv.y, acc.y);
    acc.z = fmaf(sc, wv.z, acc.z);
    acc.w = fmaf(sc, wv.w, acc.w);
}

// agent-scope relaxed load/store — device-coherent (bypass stale L1/L2),
// the exact primitive the passing baseline used for its h exchange.
__device__ __forceinline__ float lda(const float* p) {
    return __hip_atomic_load(p, __ATOMIC_RELAXED, __HIP_MEMORY_SCOPE_AGENT);
}
__device__ __forceinline__ void sta(float* p, float v) {
    __hip_atomic_store(p, v, __ATOMIC_RELAXED, __HIP_MEMORY_SCOPE_AGENT);
}

// ---------------------------------------------------------------------------
// Phase 2 scan — barrier-free point-to-point dataflow, proven primitives only.
//
// Roles: replica r = bid&7 owns batches 4r..4r+3 (32 blocks per replica);
// slot = bid>>3 owns cols slot*32..+31. Replicas never interact.
//
// out[] is write-once per (step, location) -> no WAR hazards exist, so NO
// consensus barrier is needed. Producers publish a monotonic per-(rep,slot)
// flag AFTER their step-s stores drained (the mandatory s_waitcnt vmcnt(0)
// the compiler emits before s_barrier in __syncthreads). Each consumer
// thread polls only the flag of the producer of its own k-range, then loads
// the data with agent-scope loads (same coherence point as the flag, so
// flag-visible => data-visible). Producers never wait; flags are monotonic
// -> deadlock-free by induction on steps.
//
// Poison tolerance: 0xAA... as int is NEGATIVE; consumers wait for f >= s
// (s >= 1), so un-zeroed flags cannot cause premature passes, and no other
// workspace state exists (no counters, no handshake).
// ---------------------------------------------------------------------------
__global__ __launch_bounds__(256, 1) void scan_k(const float* __restrict__ Wrec,
                                                 const float* __restrict__ bias,
                                                 const float* __restrict__ tau,
                                                 float* __restrict__ out,
                                                 int* __restrict__ ws) {
    const int t    = threadIdx.x;
    const int bid  = blockIdx.x;
    const int rep  = bid & 7;     // replica
    const int slot = bid >> 3;    // col-group within replica
    const int b0   = rep * 4;
    const int c0   = slot * 32;

    // h state [b][k], 4-dword pad per 32 k: addr(k) = k + (k>>5)*4.
    // -> conflict-free ds_write_b128 staging AND conflict-free ds_read_b128
    //    compute reads (8-lane broadcast; 36-dword group stride tiles banks).
    __shared__ __align__(16) float h_lds[4 * 1152];     // 18.4 KB
    // partials [ks][b*32+col], rows padded to 132 dwords.
    __shared__ __align__(16) float part[32 * 132];      // 16.9 KB

    // flags: one 128B-spaced slot per (rep,slot) producer. 32 KB total.
    int* const flags   = ws;
    int* const myflag  = flags + (((rep << 5) | (t >> 3)) << 5);  // my producer
    int* const pubflag = flags + (((rep << 5) | slot) << 5);      // my own flag

    // ---- one-time: W slice into registers ----
    const int ks = t >> 3;        // 0..31, k-range [ks*32, +32)
    const int cq = t & 7;         // col-quad
    const int cc = c0 + cq * 4;
    float4 wreg[32];
#pragma unroll
    for (int kk = 0; kk < 32; ++kk)
        wreg[kk] = *(const float4*)&Wrec[(size_t)(ks * 32 + kk) * H + cc];

    // ---- per-output constants for reduce threads (t<128) ----
    const int br = t >> 5, jc = t & 31;
    const int c  = c0 + jc;
    float al = 0.f, bi = 0.f;
    if (t < 128) { al = __expf(-DT / tau[c]); bi = bias[c]; }
    const size_t obase = (size_t)(b0 + br) * S * H + c;

    const int wa = 4 * t + (t >> 3) * 4;   // LDS dword offset within a b-row

    for (int s = 0; s < S; ++s) {
        if (s == 0) {
            const float4 z = make_float4(0.f, 0.f, 0.f, 0.f);
#pragma unroll
            for (int bb = 0; bb < 4; ++bb)
                *(float4*)&h_lds[bb * 1152 + wa] = z;
        } else {
            // ---- per-lane poll: only the producer of my k-range ----
            while (__hip_atomic_load(myflag, __ATOMIC_RELAXED,
                                     __HIP_MEMORY_SCOPE_AGENT) < s)
                __builtin_amdgcn_s_sleep(1);
            // ---- stage h_prev (k = 4t..4t+3, 4 batches), coherent loads ----
            const float* src = out + (size_t)(s - 1) * H + 4 * t;
            const float* s0 = src + (size_t)(b0 + 0) * S * H;
            const float* s1 = src + (size_t)(b0 + 1) * S * H;
            const float* s2 = src + (size_t)(b0 + 2) * S * H;
            const float* s3 = src + (size_t)(b0 + 3) * S * H;
            const float4 v0 = make_float4(lda(s0), lda(s0+1), lda(s0+2), lda(s0+3));
            const float4 v1 = make_float4(lda(s1), lda(s1+1), lda(s1+2), lda(s1+3));
            const float4 v2 = make_float4(lda(s2), lda(s2+1), lda(s2+2), lda(s2+3));
            const float4 v3 = make_float4(lda(s3), lda(s3+1), lda(s3+2), lda(s3+3));
            *(float4*)&h_lds[0 * 1152 + wa] = v0;
            *(float4*)&h_lds[1 * 1152 + wa] = v1;
            *(float4*)&h_lds[2 * 1152 + wa] = v2;
            *(float4*)&h_lds[3 * 1152 + wa] = v3;
        }

        // h_in for this step (plain cached load; overlaps staging latency)
        float hin = 0.f;
        if (t < 128) hin = out[obase + (size_t)s * H];

        __syncthreads();

        // ---- partials: 4 b x 4 c over my 32 k, [b][k] LDS layout ----
        float4 a0 = make_float4(0.f, 0.f, 0.f, 0.f);
        float4 a1 = a0, a2 = a0, a3 = a0;
#pragma unroll
        for (int kq = 0; kq < 8; ++kq) {
            const int ha = ks * 36 + kq * 4;
            const float4 h0 = *(const float4*)&h_lds[ha];
            const float4 h1 = *(const float4*)&h_lds[1152 + ha];
            const float4 h2 = *(const float4*)&h_lds[2304 + ha];
            const float4 h3 = *(const float4*)&h_lds[3456 + ha];
            const float r0[4] = {h0.x, h0.y, h0.z, h0.w};
            const float r1[4] = {h1.x, h1.y, h1.z, h1.w};
            const float r2[4] = {h2.x, h2.y, h2.z, h2.w};
            const float r3[4] = {h3.x, h3.y, h3.z, h3.w};
#pragma unroll
            for (int j = 0; j < 4; ++j) {
                const float4 w = wreg[kq * 4 + j];
                fma4(a0, r0[j], w);
                fma4(a1, r1[j], w);
                fma4(a2, r2[j], w);
                fma4(a3, r3[j], w);
            }
        }
        {
            float* pp = &part[ks * 132 + cq * 4];
            *(float4*)(pp +  0) = a0;
            *(float4*)(pp + 32) = a1;
            *(float4*)(pp + 64) = a2;
            *(float4*)(pp + 96) = a3;
        }
        __syncthreads();

        // ---- reduce k-split, tanh, blend, publish data (agent store) ----
        if (t < 128) {
            float sum = 0.f;
#pragma unroll
            for (int q = 0; q < 32; ++q) sum += part[q * 132 + t];
            const float z  = hin + sum + bi;
            const float e2 = __expf(2.f * z);
            const float ht = 1.f - 2.f / (e2 + 1.f);   // tanh(z)
            const float hp = h_lds[br * 1152 + slot * 36 + jc];
            const float hn = al * hp + (1.f - al) * ht;
            sta(&out[obase + (size_t)s * H], hn);
            if (s == S - 1)
                out[(size_t)B * S * H + (size_t)(b0 + br) * H + c] = hn;
        }
        // drains every wave's data stores (compiler emits vmcnt(0) before
        // s_barrier), so the flag store below is ordered after the data.
        __syncthreads();
        if (t == 0)
            __hip_atomic_store(pubflag, s + 1, __ATOMIC_RELAXED,
                               __HIP_MEMORY_SCOPE_AGENT);
        // no barrier: consumers gate themselves on the flags
    }
}

// ---------------------------------------------------------------------------
extern "C" void kernel_launch(void* const* d_in, const int* in_sizes, int n_in,
                              void* d_out, int out_size, void* d_ws, size_t ws_size,
                              hipStream_t stream) {
    (void)in_sizes; (void)n_in; (void)out_size;
    const float* x    = (const float*)d_in[0];
    const float* W_in = (const float*)d_in[1];
    const float* Wrec = (const float*)d_in[2];
    const float* bs   = (const float*)d_in[3];
    const float* tu   = (const float*)d_in[4];
    float* outp = (float*)d_out;
    int*   bwsp = (int*)d_ws;

    // zero the flag region (defensive only: logic is poison-tolerant,
    // 0xAA.. is negative as int and flags are compared with >= s, s >= 1)
    size_t zb = 256 * 32 * sizeof(int);
    if (zb > ws_size) zb = ws_size;
    (void)hipMemsetAsync(d_ws, 0, zb, stream);

    // Phase 1: input projection into the outs region of d_out
    gemm_in<<<dim3(512 * 16), dim3(256), 0, stream>>>(x, W_in, outp);

    // Phase 2: cooperative launch (co-residency guarantee), p2p dataflow
    void* kargs[5] = {(void*)&Wrec, (void*)&bs, (void*)&tu, (void*)&outp,
                      (void*)&bwsp};
    (void)hipLaunchCooperativeKernel((void*)scan_k, dim3(256), dim3(256), kargs,
                                     0, stream);
}

// Round 4
// 3435.760 us; speedup vs baseline: 2.8926x; 1.1619x over previous
//
#include <hip/hip_runtime.h>
#include <cmath>

// Problem constants (fixed by setup_inputs)
constexpr int B = 32, S = 1024, I = 512, H = 1024;
constexpr float DT = 0.05f;
// Canary: 2.0f. Exchanged values are h with |h| <~ 1.0000001 (alpha-blend of
// |h|<1 and |tanh|<=1), so the bit pattern 0x40000000 is unreachable.
constexpr unsigned CANARY = 0x40000000u;

// ---------------------------------------------------------------------------
// Phase 1: h_in_all[M=B*S][H] = x[M][I] @ W_in[I][H], fp32, written into the
// `outs` region of d_out (the scan consumes/overwrites it in place). Unchanged.
// ---------------------------------------------------------------------------
__global__ __launch_bounds__(256) void gemm_in(const float* __restrict__ A,
                                               const float* __restrict__ Bw,
                                               float* __restrict__ C) {
    const int bx = blockIdx.x;
    const int nb = bx & 15;
    const int mb = bx >> 4;
    const int t  = threadIdx.x;
    const int tx = t & 15, ty = t >> 4;

    __shared__ __align__(16) float As[16][68];
    __shared__ __align__(16) float Bs[16][68];

    float acc[4][4] = {};
    const int row0 = mb * 64, col0 = nb * 64;

    for (int kt = 0; kt < I; kt += 16) {
        {
            const int m  = t >> 2;
            const int kq = (t & 3) * 4;
            const float4 a = *(const float4*)(A + (size_t)(row0 + m) * I + kt + kq);
            As[kq + 0][m] = a.x; As[kq + 1][m] = a.y;
            As[kq + 2][m] = a.z; As[kq + 3][m] = a.w;
            const int kk = t >> 4;
            const int n4 = (t & 15) * 4;
            *(float4*)&Bs[kk][n4] =
                *(const float4*)(Bw + (size_t)(kt + kk) * H + col0 + n4);
        }
        __syncthreads();
#pragma unroll
        for (int kk = 0; kk < 16; ++kk) {
            const float4 av = *(const float4*)&As[kk][ty * 4];
            const float4 bv = *(const float4*)&Bs[kk][tx * 4];
            const float ar[4] = {av.x, av.y, av.z, av.w};
            const float br[4] = {bv.x, bv.y, bv.z, bv.w};
#pragma unroll
            for (int i = 0; i < 4; ++i)
#pragma unroll
                for (int j = 0; j < 4; ++j) acc[i][j] += ar[i] * br[j];
        }
        __syncthreads();
    }
#pragma unroll
    for (int i = 0; i < 4; ++i) {
        float4 v = make_float4(acc[i][0], acc[i][1], acc[i][2], acc[i][3]);
        *(float4*)(C + (size_t)(row0 + ty * 4 + i) * H + col0 + tx * 4) = v;
    }
}

__device__ __forceinline__ void fma4(float4& acc, float sc, const float4 wv) {
    acc.x = fmaf(sc, wv.x, acc.x);
    acc.y = fmaf(sc, wv.y, acc.y);
    acc.z = fmaf(sc, wv.z, acc.z);
    acc.w = fmaf(sc, wv.w, acc.w);
}

// agent-scope relaxed primitives (device-coherent; proven in round 2)
__device__ __forceinline__ void sta(float* p, float v) {
    __hip_atomic_store(p, v, __ATOMIC_RELAXED, __HIP_MEMORY_SCOPE_AGENT);
}
__device__ __forceinline__ unsigned long long ld2(const float* p) {
    return __hip_atomic_load((const unsigned long long*)p, __ATOMIC_RELAXED,
                             __HIP_MEMORY_SCOPE_AGENT);
}
__device__ __forceinline__ void stc(float* p, unsigned v) {
    __hip_atomic_store((unsigned*)p, v, __ATOMIC_RELAXED,
                       __HIP_MEMORY_SCOPE_AGENT);
}
__device__ __forceinline__ float uf(unsigned x) { return __uint_as_float(x); }
__device__ __forceinline__ bool has_canary(unsigned long long q) {
    return ((unsigned)q == CANARY) || ((unsigned)(q >> 32) == CANARY);
}

// ---------------------------------------------------------------------------
// Phase 2 scan — data-as-flag canary dataflow (no per-step flags, no tail
// barrier, no inline asm).
//
// Roles: replica r = bid&7 owns batches 4r..4r+3; slot = bid>>3 owns cols
// slot*32..+31. Exchanged values are h only (|h|<1 strictly, rounding <=
// ~1.0000001), so 2.0f is an impossible value and serves as a canary.
//
// Protocol per producer block, step s:
//   top:        issue plain load hinNext = out[slot(s+1)]   (own data)
//   barrier A:  (mandatory vmcnt(0)) hinNext complete
//   after A:    store CANARY -> out[slot(s+1)]              (agent relaxed)
//   barrier B:  (mandatory vmcnt(0)) canary AT coherence point
//   reduce:     h(s) = blend(...); store h -> out[slot(s)]  (agent relaxed)
// Consumer at step s+1 polls out[slot(s)] values directly until != CANARY;
// the successful poll round IS the staged data. Induction: canary(s+1) is
// at L3 before h(s) is visible; a consumer polls slot(s+1) only after
// observing h(s) => it can never read pre-canary hin garbage. Base case
// (slot 0/step 1) closed by a one-time prologue readiness flag (round-2
// flag path). Producers never wait; values are monotonic -> deadlock-free.
// Workspace: 32KB flags only; poison-tolerant (0xAA.. < 1 as int).
// ---------------------------------------------------------------------------
__global__ __launch_bounds__(256, 1) void scan_k(const float* __restrict__ Wrec,
                                                 const float* __restrict__ bias,
                                                 const float* __restrict__ tau,
                                                 float* __restrict__ out,
                                                 int* __restrict__ ws) {
    const int t    = threadIdx.x;
    const int bid  = blockIdx.x;
    const int rep  = bid & 7;
    const int slot = bid >> 3;
    const int b0   = rep * 4;
    const int c0   = slot * 32;

    __shared__ __align__(16) float h_lds[4 * 1152];     // [b][k] padded
    __shared__ __align__(16) float part[32 * 132];      // [ks][out] padded

    int* const flags   = ws;                                      // 32 KB
    int* const myflag  = flags + (((rep << 5) | (t >> 3)) << 5);  // my producer
    int* const pubflag = flags + (((rep << 5) | slot) << 5);      // my own

    // ---- one-time: W slice into registers ----
    const int ks = t >> 3;
    const int cq = t & 7;
    const int cc = c0 + cq * 4;
    float4 wreg[32];
#pragma unroll
    for (int kk = 0; kk < 32; ++kk)
        wreg[kk] = *(const float4*)&Wrec[(size_t)(ks * 32 + kk) * H + cc];

    // ---- per-output constants for reduce threads (t<128) ----
    const int br = t >> 5, jc = t & 31;
    const int c  = c0 + jc;
    float al = 0.f, bi = 0.f;
    if (t < 128) { al = __expf(-DT / tau[c]); bi = bias[c]; }
    const size_t obase = (size_t)(b0 + br) * S * H + c;

    const int wa = 4 * t + (t >> 3) * 4;

    // ---- prologue: capture hin(0), canary slot(0), publish readiness ----
    float hinCur = 0.f;
    if (t < 128) hinCur = out[obase];        // hin(0), plain load
    __syncthreads();                         // vmcnt(0): load complete
    if (t < 128) stc(&out[obase], CANARY);   // canary slot(0)
    __syncthreads();                         // vmcnt(0): canary at L3
    if (t == 0)
        __hip_atomic_store(pubflag, 1, __ATOMIC_RELAXED,
                           __HIP_MEMORY_SCOPE_AGENT);

    for (int s = 0; s < S; ++s) {
        // issue next-step hin load early (own data; never crosses blocks)
        float hinNext = 0.f;
        if (t < 128 && s + 1 < S) hinNext = out[obase + (size_t)(s + 1) * H];

        if (s == 0) {
            const float4 z = make_float4(0.f, 0.f, 0.f, 0.f);
#pragma unroll
            for (int bb = 0; bb < 4; ++bb)
                *(float4*)&h_lds[bb * 1152 + wa] = z;
        } else {
            if (s == 1) {  // one-time: producer's prologue canary is at L3
                while (__hip_atomic_load(myflag, __ATOMIC_RELAXED,
                                         __HIP_MEMORY_SCOPE_AGENT) < 1)
                    __builtin_amdgcn_s_sleep(1);
            }
            // ---- data-poll: 16 h values (4 batches x k=4t..4t+3) ----
            const float* src = out + (size_t)(s - 1) * H + 4 * t;
            const float* p0 = src + (size_t)(b0 + 0) * S * H;
            const float* p1 = src + (size_t)(b0 + 1) * S * H;
            const float* p2 = src + (size_t)(b0 + 2) * S * H;
            const float* p3 = src + (size_t)(b0 + 3) * S * H;
            unsigned long long q0, q1, q2, q3, q4, q5, q6, q7;
            for (;;) {
                q0 = ld2(p0); q1 = ld2(p0 + 2);
                q2 = ld2(p1); q3 = ld2(p1 + 2);
                q4 = ld2(p2); q5 = ld2(p2 + 2);
                q6 = ld2(p3); q7 = ld2(p3 + 2);
                const bool bad = has_canary(q0) | has_canary(q1) |
                                 has_canary(q2) | has_canary(q3) |
                                 has_canary(q4) | has_canary(q5) |
                                 has_canary(q6) | has_canary(q7);
                if (!bad) break;
                __builtin_amdgcn_s_sleep(1);
            }
            const float4 v0 = make_float4(uf((unsigned)q0), uf((unsigned)(q0 >> 32)),
                                          uf((unsigned)q1), uf((unsigned)(q1 >> 32)));
            const float4 v1 = make_float4(uf((unsigned)q2), uf((unsigned)(q2 >> 32)),
                                          uf((unsigned)q3), uf((unsigned)(q3 >> 32)));
            const float4 v2 = make_float4(uf((unsigned)q4), uf((unsigned)(q4 >> 32)),
                                          uf((unsigned)q5), uf((unsigned)(q5 >> 32)));
            const float4 v3 = make_float4(uf((unsigned)q6), uf((unsigned)(q6 >> 32)),
                                          uf((unsigned)q7), uf((unsigned)(q7 >> 32)));
            *(float4*)&h_lds[0 * 1152 + wa] = v0;
            *(float4*)&h_lds[1 * 1152 + wa] = v1;
            *(float4*)&h_lds[2 * 1152 + wa] = v2;
            *(float4*)&h_lds[3 * 1152 + wa] = v3;
        }

        __syncthreads();   // A — staging done; hinNext complete (vmcnt(0))

        // canary next step's own slot; flies during partials, drained at B
        if (t < 128 && s + 1 < S)
            stc(&out[obase + (size_t)(s + 1) * H], CANARY);

        // ---- partials: 4 b x 4 c over my 32 k ----
        float4 a0 = make_float4(0.f, 0.f, 0.f, 0.f);
        float4 a1 = a0, a2 = a0, a3 = a0;
#pragma unroll
        for (int kq = 0; kq < 8; ++kq) {
            const int ha = ks * 36 + kq * 4;
            const float4 h0 = *(const float4*)&h_lds[ha];
            const float4 h1 = *(const float4*)&h_lds[1152 + ha];
            const float4 h2 = *(const float4*)&h_lds[2304 + ha];
            const float4 h3 = *(const float4*)&h_lds[3456 + ha];
            const float r0[4] = {h0.x, h0.y, h0.z, h0.w};
            const float r1[4] = {h1.x, h1.y, h1.z, h1.w};
            const float r2[4] = {h2.x, h2.y, h2.z, h2.w};
            const float r3[4] = {h3.x, h3.y, h3.z, h3.w};
#pragma unroll
            for (int j = 0; j < 4; ++j) {
                const float4 w = wreg[kq * 4 + j];
                fma4(a0, r0[j], w);
                fma4(a1, r1[j], w);
                fma4(a2, r2[j], w);
                fma4(a3, r3[j], w);
            }
        }
        {
            float* pp = &part[ks * 132 + cq * 4];
            *(float4*)(pp +  0) = a0;
            *(float4*)(pp + 32) = a1;
            *(float4*)(pp + 64) = a2;
            *(float4*)(pp + 96) = a3;
        }
        __syncthreads();   // B — part visible; canary at L3 (vmcnt(0))

        // ---- reduce, tanh, blend, publish h (data IS the flag) ----
        if (t < 128) {
            float sum = 0.f;
#pragma unroll
            for (int q = 0; q < 32; ++q) sum += part[q * 132 + t];
            const float z  = hinCur + sum + bi;
            const float e2 = __expf(2.f * z);
            const float ht = 1.f - 2.f / (e2 + 1.f);   // tanh(z)
            const float hp = h_lds[br * 1152 + slot * 36 + jc];
            const float hn = al * hp + (1.f - al) * ht;
            sta(&out[obase + (size_t)s * H], hn);
            if (s == S - 1)
                out[(size_t)B * S * H + (size_t)(b0 + br) * H + c] = hn;
        }
        hinCur = hinNext;
        // no tail barrier: consumers gate themselves on the data values
    }
}

// ---------------------------------------------------------------------------
extern "C" void kernel_launch(void* const* d_in, const int* in_sizes, int n_in,
                              void* d_out, int out_size, void* d_ws, size_t ws_size,
                              hipStream_t stream) {
    (void)in_sizes; (void)n_in; (void)out_size;
    const float* x    = (const float*)d_in[0];
    const float* W_in = (const float*)d_in[1];
    const float* Wrec = (const float*)d_in[2];
    const float* bs   = (const float*)d_in[3];
    const float* tu   = (const float*)d_in[4];
    float* outp = (float*)d_out;
    int*   bwsp = (int*)d_ws;

    // zero flag region (defensive; logic is poison-tolerant either way)
    size_t zb = 256 * 32 * sizeof(int);
    if (zb > ws_size) zb = ws_size;
    (void)hipMemsetAsync(d_ws, 0, zb, stream);

    gemm_in<<<dim3(512 * 16), dim3(256), 0, stream>>>(x, W_in, outp);

    void* kargs[5] = {(void*)&Wrec, (void*)&bs, (void*)&tu, (void*)&outp,
                      (void*)&bwsp};
    (void)hipLaunchCooperativeKernel((void*)scan_k, dim3(256), dim3(256), kargs,
                                     0, stream);
}

// Round 5
// 3329.270 us; speedup vs baseline: 2.9851x; 1.0320x over previous
//
#include <hip/hip_runtime.h>
#include <cmath>

// Problem constants (fixed by setup_inputs)
constexpr int B = 32, S = 1024, I = 512, H = 1024;
constexpr float DT = 0.05f;
// Canary: +/-2.0f (sign bit may carry a data dependency; consumers check the
// magnitude). Exchanged values are h with |h| <= ~1.0000001, so any bit
// pattern with magnitude 2.0 (0x40000000) is unreachable by real data.
constexpr unsigned CANARY = 0x40000000u;

// ---------------------------------------------------------------------------
// Phase 1: h_in_all[M=B*S][H] = x[M][I] @ W_in[I][H], fp32, written into the
// `outs` region of d_out (the scan consumes/overwrites it in place). Unchanged.
// ---------------------------------------------------------------------------
__global__ __launch_bounds__(256) void gemm_in(const float* __restrict__ A,
                                               const float* __restrict__ Bw,
                                               float* __restrict__ C) {
    const int bx = blockIdx.x;
    const int nb = bx & 15;
    const int mb = bx >> 4;
    const int t  = threadIdx.x;
    const int tx = t & 15, ty = t >> 4;

    __shared__ __align__(16) float As[16][68];
    __shared__ __align__(16) float Bs[16][68];

    float acc[4][4] = {};
    const int row0 = mb * 64, col0 = nb * 64;

    for (int kt = 0; kt < I; kt += 16) {
        {
            const int m  = t >> 2;
            const int kq = (t & 3) * 4;
            const float4 a = *(const float4*)(A + (size_t)(row0 + m) * I + kt + kq);
            As[kq + 0][m] = a.x; As[kq + 1][m] = a.y;
            As[kq + 2][m] = a.z; As[kq + 3][m] = a.w;
            const int kk = t >> 4;
            const int n4 = (t & 15) * 4;
            *(float4*)&Bs[kk][n4] =
                *(const float4*)(Bw + (size_t)(kt + kk) * H + col0 + n4);
        }
        __syncthreads();
#pragma unroll
        for (int kk = 0; kk < 16; ++kk) {
            const float4 av = *(const float4*)&As[kk][ty * 4];
            const float4 bv = *(const float4*)&Bs[kk][tx * 4];
            const float ar[4] = {av.x, av.y, av.z, av.w};
            const float br[4] = {bv.x, bv.y, bv.z, bv.w};
#pragma unroll
            for (int i = 0; i < 4; ++i)
#pragma unroll
                for (int j = 0; j < 4; ++j) acc[i][j] += ar[i] * br[j];
        }
        __syncthreads();
    }
#pragma unroll
    for (int i = 0; i < 4; ++i) {
        float4 v = make_float4(acc[i][0], acc[i][1], acc[i][2], acc[i][3]);
        *(float4*)(C + (size_t)(row0 + ty * 4 + i) * H + col0 + tx * 4) = v;
    }
}

// fma of scalar into 2-wide accumulator
__device__ __forceinline__ void fma2(float2& acc, float sc, const float2 wv) {
    acc.x = fmaf(sc, wv.x, acc.x);
    acc.y = fmaf(sc, wv.y, acc.y);
}

// agent-scope relaxed primitives (device-coherent; proven rounds 2/4)
__device__ __forceinline__ void sta(float* p, float v) {
    __hip_atomic_store(p, v, __ATOMIC_RELAXED, __HIP_MEMORY_SCOPE_AGENT);
}
__device__ __forceinline__ unsigned long long ld2(const float* p) {
    return __hip_atomic_load((const unsigned long long*)p, __ATOMIC_RELAXED,
                             __HIP_MEMORY_SCOPE_AGENT);
}
__device__ __forceinline__ void stc(float* p, unsigned v) {
    __hip_atomic_store((unsigned*)p, v, __ATOMIC_RELAXED,
                       __HIP_MEMORY_SCOPE_AGENT);
}
__device__ __forceinline__ float uf(unsigned x) { return __uint_as_float(x); }
// magnitude-masked canary check (canary sign bit may carry data dependency)
__device__ __forceinline__ bool has_canary(unsigned long long q) {
    return (((unsigned)q & 0x7FFFFFFFu) == CANARY) ||
           (((unsigned)(q >> 32) & 0x7FFFFFFFu) == CANARY);
}

// ---------------------------------------------------------------------------
// Phase 2 scan — canary dataflow (round-4 proven) + single-barrier pipeline:
//   * 512 threads/block (8 waves), 2 cols/thread, SAME 32-k chunks and SAME
//     FP accumulation order as round 4 (bit-exact results).
//   * thread map t = ks*16 + cq2: each k-chunk ks is staged AND consumed by
//     the same 16 lanes of one wave -> staging->partials needs NO barrier
//     (CDNA waves are lockstep; LDS pipe is in-order per wave; the compiler
//     cannot reorder may-aliasing LDS ops).
//   * part[] double-buffered by step parity: step-(s+1) partials (computed by
//     fast waves while waves 0-1 still reduce step s) cannot race the reduce.
//   * the ONLY per-step barrier is B (cross-wave partials gather). Its
//     mandatory vmcnt(0) drain keeps the canary-before-publish ordering of
//     the round-4 protocol intact.
//   * hinNext (plain load) vs same-address canary store: ordered by making
//     the canary value depend on hinNext's sign bit (register dependency).
// h_lds cross-step hazards are self-gated: a chunk group overwrites only its
// own region, and the own-slot region (read as hp by the reduce) is re-staged
// only after the group observes this block's OWN publish, which the reduce
// issues strictly after the hp read.
// ---------------------------------------------------------------------------
__global__ __launch_bounds__(512, 1) void scan_k(const float* __restrict__ Wrec,
                                                 const float* __restrict__ bias,
                                                 const float* __restrict__ tau,
                                                 float* __restrict__ out,
                                                 int* __restrict__ ws) {
    const int t    = threadIdx.x;
    const int bid  = blockIdx.x;
    const int rep  = bid & 7;
    const int slot = bid >> 3;
    const int b0   = rep * 4;
    const int c0   = slot * 32;

    const int ks  = t >> 4;       // 0..31: k-chunk = producer slot index
    const int cq2 = t & 15;       // 0..15: 2-col group

    __shared__ __align__(16) float h_lds[4 * 1152];     // [b][k] padded, 18.4KB
    __shared__ __align__(16) float part[2][32 * 132];   // dbuf, 33.8KB

    int* const flags   = ws;                                    // 32 KB
    int* const myflag  = flags + (((rep << 5) | ks) << 5);      // my producer
    int* const pubflag = flags + (((rep << 5) | slot) << 5);    // my own

    // ---- one-time: W slice into registers (32 k x 2 cols = 64 VGPR) ----
    const int cc = c0 + cq2 * 2;
    float2 wreg[32];
#pragma unroll
    for (int kk = 0; kk < 32; ++kk)
        wreg[kk] = *(const float2*)&Wrec[(size_t)(ks * 32 + kk) * H + cc];

    // ---- per-output constants for reduce threads (t<128) ----
    const int br = t >> 5, jc = t & 31;       // meaningful only for t<128
    const int c  = c0 + jc;
    float al = 0.f, bi = 0.f;
    if (t < 128) { al = __expf(-DT / tau[c]); bi = bias[c]; }
    const size_t obase = (size_t)(b0 + br) * S * H + c;

    const int wa2 = 2 * t + ks * 4;   // LDS dword offset of k=2t (padded)

    // ---- prologue: capture hin(0), canary slot(0), publish readiness ----
    float hinCur = 0.f;
    if (t < 128) hinCur = out[obase];        // hin(0), plain load
    __syncthreads();                         // vmcnt(0): load complete
    if (t < 128) stc(&out[obase], CANARY);   // canary slot(0)
    __syncthreads();                         // vmcnt(0): canary at L3
    if (t == 0)
        __hip_atomic_store(pubflag, 1, __ATOMIC_RELAXED,
                           __HIP_MEMORY_SCOPE_AGENT);

    for (int s = 0; s < S; ++s) {
        // next-step hin load early (own data; never crosses blocks)
        float hinNext = 0.f;
        if (t < 128 && s + 1 < S) hinNext = out[obase + (size_t)(s + 1) * H];

        if (s == 0) {
            const float2 z = make_float2(0.f, 0.f);
#pragma unroll
            for (int bb = 0; bb < 4; ++bb)
                *(float2*)&h_lds[bb * 1152 + wa2] = z;
        } else {
            if (s == 1) {  // one-time: producer's prologue canary is at L3
                while (__hip_atomic_load(myflag, __ATOMIC_RELAXED,
                                         __HIP_MEMORY_SCOPE_AGENT) < 1)
                    __builtin_amdgcn_s_sleep(1);
            }
            // ---- data-poll: 8 h values (4 batches x k=2t..2t+1) ----
            const float* src = out + (size_t)(s - 1) * H + 2 * t;
            const float* p0 = src + (size_t)(b0 + 0) * S * H;
            const float* p1 = src + (size_t)(b0 + 1) * S * H;
            const float* p2 = src + (size_t)(b0 + 2) * S * H;
            const float* p3 = src + (size_t)(b0 + 3) * S * H;
            unsigned long long q0, q1, q2, q3;
            for (;;) {
                q0 = ld2(p0); q1 = ld2(p1); q2 = ld2(p2); q3 = ld2(p3);
                const bool bad = has_canary(q0) | has_canary(q1) |
                                 has_canary(q2) | has_canary(q3);
                if (!bad) break;
                __builtin_amdgcn_s_sleep(1);
            }
            *(float2*)&h_lds[0 * 1152 + wa2] =
                make_float2(uf((unsigned)q0), uf((unsigned)(q0 >> 32)));
            *(float2*)&h_lds[1 * 1152 + wa2] =
                make_float2(uf((unsigned)q1), uf((unsigned)(q1 >> 32)));
            *(float2*)&h_lds[2 * 1152 + wa2] =
                make_float2(uf((unsigned)q2), uf((unsigned)(q2 >> 32)));
            *(float2*)&h_lds[3 * 1152 + wa2] =
                make_float2(uf((unsigned)q3), uf((unsigned)(q3 >> 32)));
        }

        // canary next step's own slot; value depends on hinNext (sign bit)
        // so the store cannot pass the outstanding hinNext load.
        if (t < 128 && s + 1 < S) {
            const unsigned cb =
                CANARY | (__float_as_uint(hinNext) & 0x80000000u);
            stc(&out[obase + (size_t)(s + 1) * H], cb);
        }

        // ---- partials: 4 b x 2 c over my 32 k (wave-local LDS data) ----
        float2 a0 = make_float2(0.f, 0.f);
        float2 a1 = a0, a2 = a0, a3 = a0;
#pragma unroll
        for (int kq = 0; kq < 8; ++kq) {
            const int ha = ks * 36 + kq * 4;
            const float4 h0 = *(const float4*)&h_lds[ha];
            const float4 h1 = *(const float4*)&h_lds[1152 + ha];
            const float4 h2 = *(const float4*)&h_lds[2304 + ha];
            const float4 h3 = *(const float4*)&h_lds[3456 + ha];
            const float r0[4] = {h0.x, h0.y, h0.z, h0.w};
            const float r1[4] = {h1.x, h1.y, h1.z, h1.w};
            const float r2[4] = {h2.x, h2.y, h2.z, h2.w};
            const float r3[4] = {h3.x, h3.y, h3.z, h3.w};
#pragma unroll
            for (int j = 0; j < 4; ++j) {
                const float2 w = wreg[kq * 4 + j];
                fma2(a0, r0[j], w);
                fma2(a1, r1[j], w);
                fma2(a2, r2[j], w);
                fma2(a3, r3[j], w);
            }
        }
        {
            float* pp = &part[s & 1][ks * 132 + cq2 * 2];
            *(float2*)(pp +  0) = a0;
            *(float2*)(pp + 32) = a1;
            *(float2*)(pp + 64) = a2;
            *(float2*)(pp + 96) = a3;
        }
        __syncthreads();   // B — partials visible; canary at L3 (vmcnt(0))

        // ---- reduce, tanh, blend, publish h (data IS the flag) ----
        if (t < 128) {
            const float* pb = &part[s & 1][0];
            float sum = 0.f;
#pragma unroll
            for (int q = 0; q < 32; ++q) sum += pb[q * 132 + t];
            const float z  = hinCur + sum + bi;
            const float e2 = __expf(2.f * z);
            const float ht = 1.f - 2.f / (e2 + 1.f);   // tanh(z)
            const float hp = h_lds[br * 1152 + slot * 36 + jc];
            const float hn = al * hp + (1.f - al) * ht;
            sta(&out[obase + (size_t)s * H], hn);
            if (s == S - 1)
                out[(size_t)B * S * H + (size_t)(b0 + br) * H + c] = hn;
        }
        hinCur = hinNext;
        // no tail barrier, no staging barrier: waves gate themselves on the
        // canary data; part is double-buffered; h_lds regions are wave-local.
    }
}

// ---------------------------------------------------------------------------
extern "C" void kernel_launch(void* const* d_in, const int* in_sizes, int n_in,
                              void* d_out, int out_size, void* d_ws, size_t ws_size,
                              hipStream_t stream) {
    (void)in_sizes; (void)n_in; (void)out_size;
    const float* x    = (const float*)d_in[0];
    const float* W_in = (const float*)d_in[1];
    const float* Wrec = (const float*)d_in[2];
    const float* bs   = (const float*)d_in[3];
    const float* tu   = (const float*)d_in[4];
    float* outp = (float*)d_out;
    int*   bwsp = (int*)d_ws;

    // zero flag region (defensive; logic is poison-tolerant either way)
    size_t zb = 256 * 32 * sizeof(int);
    if (zb > ws_size) zb = ws_size;
    (void)hipMemsetAsync(d_ws, 0, zb, stream);

    gemm_in<<<dim3(512 * 16), dim3(256), 0, stream>>>(x, W_in, outp);

    void* kargs[5] = {(void*)&Wrec, (void*)&bs, (void*)&tu, (void*)&outp,
                      (void*)&bwsp};
    (void)hipLaunchCooperativeKernel((void*)scan_k, dim3(256), dim3(512), kargs,
                                     0, stream);
}